// Round 15
// baseline (937.885 us; speedup 1.0000x reference)
//
#include <hip/hip_runtime.h>
#include <hip/hip_fp16.h>

#define NN   100000
#define E0   1600000
#define ET   1700000
#define NEG  0.2f
#define EPSV 1e-16f
#define NB2  782            // dst buckets of 128 node ids
#define BS   1024
#define NBLK4 ((ET + 4 * BS - 1) / (4 * BS))   // 416, 4 edges/thread

typedef _Float16 half8 __attribute__((ext_vector_type(8)));
typedef float f32x16 __attribute__((ext_vector_type(16)));

// ---- bucket counts: LDS-aggregated histogram, 4 edges/thread ----
__global__ __launch_bounds__(BS) void k_bcount(const int* __restrict__ ei, int* __restrict__ bcnt)
{
    __shared__ int cnt[NB2];
    int t = threadIdx.x;
    if (t < NB2) cnt[t] = 0;
    __syncthreads();
    int base = blockIdx.x * (BS * 4);
#pragma unroll
    for (int k = 0; k < 4; ++k) {
        int idx = base + k * BS + t;
        if (idx < ET) {
            int d = (idx < E0) ? ei[E0 + idx] : (idx - E0);
            atomicAdd(&cnt[d >> 7], 1);
        }
    }
    __syncthreads();
    if (t < NB2 && cnt[t]) atomicAdd(&bcnt[t], cnt[t]);
}

// ---- exclusive scan of 782 bucket counts -> bbase, bcursor ----
__global__ __launch_bounds__(1024) void k_bscan(const int* __restrict__ bcnt,
                                                int* __restrict__ bbase, int* __restrict__ bcursor)
{
    int t = threadIdx.x;
    int v = (t < NB2) ? bcnt[t] : 0;
    int lane = t & 63, wid = t >> 6;
    int sc = v;
#pragma unroll
    for (int off = 1; off < 64; off <<= 1) {
        int u = __shfl_up(sc, off, 64);
        if (lane >= off) sc += u;
    }
    __shared__ int wsum[16];
    if (lane == 63) wsum[wid] = sc;
    __syncthreads();
    int woff = 0;
    for (int k = 0; k < wid; ++k) woff += wsum[k];
    if (t < NB2) { int e = sc + woff - v; bbase[t] = e; bcursor[t] = e; }
}

// ---- bin edges by dst bucket, 4 edges/thread; record = s | (d&127)<<17 ----
__global__ __launch_bounds__(BS) void k_bscat(const int* __restrict__ ei,
                                              int* __restrict__ bcursor, int* __restrict__ bin)
{
    __shared__ int cnt[NB2];
    __shared__ int base[NB2];
    int t = threadIdx.x;
    if (t < NB2) cnt[t] = 0;
    __syncthreads();
    int blk = blockIdx.x * (BS * 4);
    int b[4], r[4], pk[4];
#pragma unroll
    for (int k = 0; k < 4; ++k) {
        int idx = blk + k * BS + t;
        r[k] = -1;
        if (idx < ET) {
            int s, d;
            if (idx < E0) { s = ei[idx]; d = ei[E0 + idx]; } else { s = d = idx - E0; }
            b[k] = d >> 7;
            pk[k] = s | ((d & 127) << 17);
            r[k] = atomicAdd(&cnt[b[k]], 1);
        }
    }
    __syncthreads();
    if (t < NB2 && cnt[t]) base[t] = atomicAdd(&bcursor[t], cnt[t]);
    __syncthreads();
#pragma unroll
    for (int k = 0; k < 4; ++k)
        if (r[k] >= 0) bin[base[b[k]] + r[k]] = pk[k];
}

// ---- Layer 1 GEMM via MFMA (unchanged from R14). ----
__global__ __launch_bounds__(256) void k_gemm1(
    const float* __restrict__ x, const float* __restrict__ W1,
    const float* __restrict__ as1, const float* __restrict__ ad1,
    __half* __restrict__ h1h, float* __restrict__ asrc1, float* __restrict__ adst1)
{
    __shared__ float Wl[4096];
    __shared__ float Ul[512];
    int tid = threadIdx.x;
    for (int i = tid; i < 4096; i += 256) Wl[i] = W1[i];
    __syncthreads();
    if (tid < 64) {
        int k = tid;
#pragma unroll
        for (int h = 0; h < 4; ++h) {
            float su = 0.f, du = 0.f;
#pragma unroll
            for (int c = 0; c < 16; ++c) {
                float w = Wl[k * 64 + h * 16 + c];
                su += w * as1[h * 16 + c];
                du += w * ad1[h * 16 + c];
            }
            Ul[k * 8 + h] = su;
            Ul[k * 8 + 4 + h] = du;
        }
    }
    __syncthreads();
    int lane = tid & 63, wv = tid >> 6;
    int col = lane & 31, q = lane >> 5;

    half8 bf0[4], bf1[4], bf2[4];
#pragma unroll
    for (int kc = 0; kc < 4; ++kc) {
#pragma unroll
        for (int j = 0; j < 8; ++j) {
            int k = kc * 16 + q * 8 + j;
            bf0[kc][j] = (_Float16)Wl[k * 64 + col];
            bf1[kc][j] = (_Float16)Wl[k * 64 + 32 + col];
            bf2[kc][j] = (col < 8) ? (_Float16)Ul[k * 8 + col] : (_Float16)0.f;
        }
    }

    int tile = blockIdx.x * 4 + wv;
    int n0 = tile * 32;
    if (n0 >= NN) return;

    half8 af[4];
    const float* xrow = x + (size_t)(n0 + col) * 64;
#pragma unroll
    for (int kc = 0; kc < 4; ++kc) {
        float4 xa = *(const float4*)(xrow + kc * 16 + q * 8);
        float4 xb = *(const float4*)(xrow + kc * 16 + q * 8 + 4);
        af[kc][0] = (_Float16)xa.x; af[kc][1] = (_Float16)xa.y;
        af[kc][2] = (_Float16)xa.z; af[kc][3] = (_Float16)xa.w;
        af[kc][4] = (_Float16)xb.x; af[kc][5] = (_Float16)xb.y;
        af[kc][6] = (_Float16)xb.z; af[kc][7] = (_Float16)xb.w;
    }

    f32x16 c0 = {}, c1 = {}, c2 = {};
#pragma unroll
    for (int kc = 0; kc < 4; ++kc) {
        c0 = __builtin_amdgcn_mfma_f32_32x32x16_f16(af[kc], bf0[kc], c0, 0, 0, 0);
        c1 = __builtin_amdgcn_mfma_f32_32x32x16_f16(af[kc], bf1[kc], c1, 0, 0, 0);
        c2 = __builtin_amdgcn_mfma_f32_32x32x16_f16(af[kc], bf2[kc], c2, 0, 0, 0);
    }

#pragma unroll
    for (int reg = 0; reg < 16; ++reg) {
        int row = (reg & 3) + 8 * (reg >> 2) + 4 * q;
        h1h[(size_t)(n0 + row) * 64 + col]      = __float2half(c0[reg]);
        h1h[(size_t)(n0 + row) * 64 + 32 + col] = __float2half(c1[reg]);
    }
    if (col < 8) {
        float* dst = (col < 4) ? asrc1 : adst1;
        int h = col & 3;
#pragma unroll
        for (int reg = 0; reg < 16; ++reg) {
            int row = (reg & 3) + 8 * (reg >> 2) + 4 * q;
            dst[(n0 + row) * 4 + h] = c2[reg];
        }
    }
}

// ---- Layer 1 aggregation: EDGE-PARALLEL on unordered bin records.
// Block = 128-node dst bucket; LDS accumulators (32KB) + f32 LDS atomics.
// 2 edges/wave, 32 lanes/edge (half2 per lane). Perfect load balance,
// no csr/rowptr needed. Epilogue: normalize, ELU, W2-dot -> g. ----
__global__ __launch_bounds__(256) void k_e1agg(
    const int* __restrict__ bin, const int* __restrict__ bbase, const int* __restrict__ bcnt,
    const float* __restrict__ asrc1, const float* __restrict__ adst1,
    const __half* __restrict__ h1h, const float* __restrict__ b1,
    const float* __restrict__ W2, float* __restrict__ g)
{
    __shared__ float acc[128 * 64];   // 32 KB
    __shared__ float den[128 * 4];
    __shared__ float ads[128 * 4];
    int b = blockIdx.x;
    int n0 = b << 7;
    int t = threadIdx.x;
    for (int i = t; i < 8192; i += 256) acc[i] = 0.f;
    for (int i = t; i < 512; i += 256) {
        den[i] = 0.f;
        int gi = n0 * 4 + i;
        ads[i] = (gi < NN * 4) ? adst1[gi] : 0.f;
    }
    __syncthreads();
    int beg = bbase[b], cnt = bcnt[b];
    int lane = t & 63;
    int sub = lane >> 5;        // which of 2 edges in this wave-iter
    int c2  = lane & 31;        // channel pair (2*c2, 2*c2+1)
    int h   = c2 >> 3;          // head
    int wv  = t >> 6;
    for (int i = wv * 2 + sub; i < cnt; i += 8) {
        int rec = bin[beg + i];
        int s  = rec & 0x1FFFF;
        int dl = rec >> 17;
        float a = asrc1[s * 4 + h] + ads[dl * 4 + h];
        a = a > 0.f ? a : NEG * a;
        float ev = __expf(a);
        float2 f = __half22float2(*(const __half2*)(h1h + (size_t)s * 64 + c2 * 2));
        atomicAdd(&acc[dl * 64 + c2 * 2],     ev * f.x);
        atomicAdd(&acc[dl * 64 + c2 * 2 + 1], ev * f.y);
        if ((c2 & 7) == 0) atomicAdd(&den[dl * 4 + h], ev);
    }
    __syncthreads();
    // epilogue: 2 threads per node (32 channels each)
    int nl = t >> 1, half = t & 1;
    int n = n0 + nl;
    if (n < NN) {
        float gv = 0.f;
#pragma unroll
        for (int h2 = 0; h2 < 2; ++h2) {
            int hh = half * 2 + h2;
            float inv = 1.f / (den[nl * 4 + hh] + EPSV);
#pragma unroll
            for (int c = 0; c < 16; ++c) {
                int ch = hh * 16 + c;
                float v = acc[nl * 64 + ch] * inv + b1[ch];
                v = v > 0.f ? v : __expf(v) - 1.f;
                gv += v * W2[ch];
            }
        }
        gv += __shfl_xor(gv, 1);
        if (half == 0) g[n] = gv;
    }
}

// ---- Layer 2 aggregation: edge-parallel on bin, LDS acc/den per node ----
__global__ __launch_bounds__(256) void k_e2agg(
    const int* __restrict__ bin, const int* __restrict__ bbase, const int* __restrict__ bcnt,
    const float* __restrict__ g, const float* __restrict__ as2,
    const float* __restrict__ ad2, const float* __restrict__ b2,
    float* __restrict__ out)
{
    __shared__ float accD[128], denD[128], gd[128];
    int b = blockIdx.x;
    int n0 = b << 7;
    int t = threadIdx.x;
    if (t < 128) {
        accD[t] = 0.f; denD[t] = 0.f;
        int n = n0 + t;
        gd[t] = (n < NN) ? g[n] * ad2[0] : 0.f;
    }
    __syncthreads();
    float cs = as2[0];
    int beg = bbase[b], cnt = bcnt[b];
    for (int i = t; i < cnt; i += 256) {
        int rec = bin[beg + i];
        int s  = rec & 0x1FFFF;
        int dl = rec >> 17;
        float gz = g[s];
        float a = gz * cs + gd[dl];
        a = a > 0.f ? a : NEG * a;
        float ev = __expf(a);
        atomicAdd(&denD[dl], ev);
        atomicAdd(&accD[dl], ev * gz);
    }
    __syncthreads();
    if (t < 128) {
        int n = n0 + t;
        if (n < NN) out[n] = accD[t] / (denD[t] + EPSV) + b2[0];
    }
}

extern "C" void kernel_launch(void* const* d_in, const int* in_sizes, int n_in,
                              void* d_out, int out_size, void* d_ws, size_t ws_size,
                              hipStream_t stream)
{
    const float* x   = (const float*)d_in[0];
    const int*   ei  = (const int*)d_in[1];
    const float* W1  = (const float*)d_in[2];
    const float* as1 = (const float*)d_in[3];
    const float* ad1 = (const float*)d_in[4];
    const float* b1  = (const float*)d_in[5];
    const float* W2  = (const float*)d_in[6];
    const float* as2 = (const float*)d_in[7];
    const float* ad2 = (const float*)d_in[8];
    const float* b2  = (const float*)d_in[9];
    float* out = (float*)d_out;

    // workspace layout (4-byte units)
    int*   iw      = (int*)d_ws;
    float* fw      = (float*)d_ws;
    int*   bcnt    = iw;                  //      782
    int*   bbase   = iw + 896;            //      782
    int*   bcursor = iw + 1792;           //      782
    int*   bin     = iw + 2688;           // 1,700,000
    float* asrc1   = fw + 1702784;        //   400,000
    float* adst1   = fw + 2102784;        //   400,000
    float* g       = fw + 2502784;        //   100,000
    __half* h1h    = (__half*)(fw + 2602880); // 6.4M halves = 3.2M slots
    // total ≈ 5.8M slots ≈ 23.2 MB

    hipMemsetAsync(bcnt, 0, NB2 * sizeof(int), stream);

    k_bcount<<<NBLK4, BS, 0, stream>>>(ei, bcnt);
    k_bscan <<<1, 1024, 0, stream>>>(bcnt, bbase, bcursor);
    k_bscat <<<NBLK4, BS, 0, stream>>>(ei, bcursor, bin);
    k_gemm1 <<<(NN / 32 + 3) / 4, 256, 0, stream>>>(x, W1, as1, ad1, h1h, asrc1, adst1);
    k_e1agg <<<NB2, 256, 0, stream>>>(bin, bbase, bcnt, asrc1, adst1, h1h, b1, W2, g);
    k_e2agg <<<NB2, 256, 0, stream>>>(bin, bbase, bcnt, g, as2, ad2, b2, out);
}